// Round 8
// baseline (320.923 us; speedup 1.0000x reference)
//
#include <hip/hip_runtime.h>
#include <hip/hip_cooperative_groups.h>
#include <math.h>

namespace cg = cooperative_groups;

// Problem constants (match reference)
constexpr int Nn   = 8192;
constexpr int Ee   = 4096;
constexpr int DIN  = 256;
constexpr int DOUT = 128;
constexpr int NNZ  = 65536;
constexpr int EC   = 96;   // capacity: nodes per edge (deg ~ Poisson(16))
constexpr int NC   = 48;   // capacity: edges per node (deg ~ Poisson(8))
constexpr int CBLK = 256;  // cooperative blocks (1/CU)
constexpr int CTHR = 1024; // threads/block -> 16 waves/CU, VGPR capped at 128
constexpr int CWAV = CBLK * CTHR / 64;   // 4096 waves

#define TEMPR 0.08838834764831845f   // 1/sqrt(128)
#define EM1   1.7182818284590452f    // e - 1

typedef __attribute__((ext_vector_type(8))) short short8;
typedef __attribute__((ext_vector_type(4))) float f32x4;

static __device__ __forceinline__ float wave_sum64(float v) {
#pragma unroll
    for (int m = 32; m; m >>= 1) v += __shfl_xor(v, m, 64);
    return v;
}
static __device__ __forceinline__ float wave_max64(float v) {
#pragma unroll
    for (int m = 32; m; m >>= 1) v = fmaxf(v, __shfl_xor(v, m, 64));
    return v;
}
static __device__ __forceinline__ short f2bf(float f) {
    union { float f; unsigned u; } v; v.f = f;
    const unsigned r = (v.u + 0x7FFFu + ((v.u >> 16) & 1u)) >> 16;
    return (short)r;
}
static __device__ __forceinline__ unsigned packbf2(float a, float b) {
    return ((unsigned)(unsigned short)f2bf(a)) |
           (((unsigned)(unsigned short)f2bf(b)) << 16);
}
static __device__ __forceinline__ float2 unpackbf2(unsigned u) {
    union { unsigned u; float f; } lo, hi;
    lo.u = u << 16; hi.u = u & 0xFFFF0000u;
    return make_float2(lo.f, hi.f);
}

struct Prm {
    const float* x; const float* W; const float* W2; const float* W3;
    const float* bias; const float* q; const int* hidx;
    void* zbase; unsigned zTotal16;
    unsigned* bitmap; int* degE; int* degN;
    float* wsArr; float* c2g;
    float* csx4; float* csxw; float* vxg; float* twxg; float* wsxg;
    short* x4b; short* xwb; float* rowv; float* vArr;
    int* csrEn; float* Sval; float* Tval; int* csrNe; int* csrNs;
    unsigned* e4b; unsigned* G1b; unsigned* G2b;
    short* W2T; short* WWT; float* bW3;
    float* out;
};

union SMem {
    struct {                                  // P1 gemm epilogues
        float s4[DOUT]; float sw[DOUT]; float srow[2][16];
    } g;
    struct {                                  // P2 edge phase (per-wave)
        int sN[16][EC]; float sS[16][EC]; float c2s[16];
    } e;
    struct {                                  // P3 node2
        float sx[16][DOUT];
        float a[DOUT]; float b[DOUT]; float c[DOUT];
    } r;
};

__global__ __launch_bounds__(CTHR) void mega2(Prm p)
{
    __shared__ SMem sm;
    cg::grid_group grid = cg::this_grid();

    const int t    = threadIdx.x;
    const int lane = t & 63;
    const int w    = t >> 6;                      // wave in block, 0..15
    const unsigned gid = blockIdx.x * CTHR + t;   // 0..262143
    const int u    = blockIdx.x * 16 + w;         // global wave id, 0..4095
    const int n16  = lane & 15;
    const int quad = lane >> 4;

    // ===== P0: ww3 prologue (gid < 10368) + zero z-region (rest) ============
    if (gid < 8192) {                      // WW3 = W @ W3 -> WWT[c][r] bf16
        const int b  = gid >> 8;
        const int tt = gid & 255;
        const int c  = tt & 127;
        const int rh = (tt >> 7) * 4;
        const int r0 = b * 8;
        float acc[4] = {0.f, 0.f, 0.f, 0.f};
        for (int k = 0; k < 128; ++k) {
            const float w3 = p.W3[(size_t)k * DOUT + c];
#pragma unroll
            for (int i = 0; i < 4; ++i)
                acc[i] = fmaf(p.W[(size_t)(r0 + rh + i) * DOUT + k], w3, acc[i]);
        }
#pragma unroll
        for (int i = 0; i < 4; ++i)
            p.WWT[(size_t)c * DIN + (r0 + rh + i)] = f2bf(acc[i]);
    } else if (gid < 10240) {              // W2 transpose -> W2T[n][k] bf16
        const int idx = gid - 8192;
        const int k0  = (idx >> 8) * 32;
        const int tt  = idx & 255;
        for (int i = tt; i < 32 * 128; i += 256) {
            const int k = k0 + (i >> 7);
            const int n = i & 127;
            p.W2T[(size_t)n * DIN + k] = f2bf(p.W2[(size_t)k * DOUT + n]);
        }
    } else if (gid < 10368) {              // bW3 = bias @ W3
        const int c = gid - 10240;
        float acc = 0.f;
        for (int k = 0; k < 128; ++k)
            acc = fmaf(p.bias[k], p.W3[(size_t)k * DOUT + c], acc);
        p.bW3[c] = acc;
    } else {                               // zero bitmap + accumulators
        uint4 z; z.x = z.y = z.z = z.w = 0u;
        uint4* zp = (uint4*)p.zbase;
        for (unsigned i = gid - 10368; i < p.zTotal16; i += CBLK * CTHR - 10368)
            zp[i] = z;
    }
    grid.sync();

    // ===== P1: CSR build + MFMA GEMM (8 waves per 16-row tile) ==============
    if (gid < NNZ) {
        const int n = p.hidx[gid];
        const int e = p.hidx[NNZ + gid];
        const unsigned word = (unsigned)n * (unsigned)Ee + (unsigned)e;
        const unsigned bit  = 1u << (word & 31u);
        const unsigned old  = atomicOr(&p.bitmap[word >> 5], bit);
        if (!(old & bit)) {
            const int pe = atomicAdd(&p.degE[e], 1);
            if (pe < EC) {
                p.csrEn[e * EC + pe] = n;
                const int pn = atomicAdd(&p.degN[n], 1);
                if (pn < NC) {
                    p.csrNe[n * NC + pn] = e;
                    p.csrNs[n * NC + pn] = e * EC + pe;
                }
            }
        }
    }
    {
        const int tile = u >> 3;               // 0..511
        const int r0   = tile * 16;
        const int col0 = (u & 7) * 16;
        const int col  = col0 + n16;
        f32x4 acc4 = (f32x4){0.f, 0.f, 0.f, 0.f};
        f32x4 accw = (f32x4){0.f, 0.f, 0.f, 0.f};
#pragma unroll
        for (int k0 = 0; k0 < DIN; k0 += 32) {
            const int kb = k0 + quad * 8;
            const float4 xa = *(const float4*)&p.x[(size_t)(r0 + n16) * DIN + kb];
            const float4 xb = *(const float4*)&p.x[(size_t)(r0 + n16) * DIN + kb + 4];
            short8 af;
            af[0] = f2bf(xa.x); af[1] = f2bf(xa.y); af[2] = f2bf(xa.z); af[3] = f2bf(xa.w);
            af[4] = f2bf(xb.x); af[5] = f2bf(xb.y); af[6] = f2bf(xb.z); af[7] = f2bf(xb.w);
            const short8 b4 = *(const short8*)&p.W2T[(size_t)col * DIN + kb];
            const short8 bw = *(const short8*)&p.WWT[(size_t)col * DIN + kb];
            acc4 = __builtin_amdgcn_mfma_f32_16x16x32_bf16(af, b4, acc4, 0, 0, 0);
            accw = __builtin_amdgcn_mfma_f32_16x16x32_bf16(af, bw, accw, 0, 0, 0);
        }
        const float bwv = p.bW3[col];
        const float qv  = p.q[col];
#pragma unroll
        for (int reg = 0; reg < 4; ++reg) {
            const int row = r0 + quad * 4 + reg;
            p.x4b[(size_t)row * DOUT + col] = f2bf(acc4[reg]);
            p.xwb[(size_t)row * DOUT + col] = f2bf(accw[reg] + bwv);
        }
        // epilogues
        float pr[4];
#pragma unroll
        for (int reg = 0; reg < 4; ++reg) pr[reg] = qv * acc4[reg];
#pragma unroll
        for (int m = 8; m; m >>= 1) {
#pragma unroll
            for (int reg = 0; reg < 4; ++reg) pr[reg] += __shfl_xor(pr[reg], m, 64);
        }
        if (t < 32) sm.g.srow[t >> 4][t & 15] = 0.f;
        if (t < DOUT) { sm.g.s4[t] = 0.f; sm.g.sw[t] = 0.f; }
        __syncthreads();
        const int team = w >> 3;               // 0,1 (tile = blockIdx.x*2+team)
        if (n16 == 0) {
#pragma unroll
            for (int reg = 0; reg < 4; ++reg)
                atomicAdd(&sm.g.srow[team][quad * 4 + reg], pr[reg]);
        }
        const float c4s = acc4[0] + acc4[1] + acc4[2] + acc4[3];
        const float cws = accw[0] + accw[1] + accw[2] + accw[3] + 4.f * bwv;
        atomicAdd(&sm.g.s4[col], c4s);
        atomicAdd(&sm.g.sw[col], cws);
        __syncthreads();
        if (t < 32)
            p.rowv[(blockIdx.x * 2 + (t >> 4)) * 16 + (t & 15)] =
                sm.g.srow[t >> 4][t & 15] * TEMPR;
        if (t < DOUT) {
            atomicAdd(&p.csx4[t], sm.g.s4[t]);
            atomicAdd(&p.csxw[t], sm.g.sw[t]);
        }
    }
    grid.sync();

    // ===== P2: per-edge softmax1 + gathers (e4b, G1b) + ws scatter ==========
    {
        const int e   = u;
        const int deg = min(p.degE[e], EC);
        const float ue = deg ? 1.0f / ((float)Nn + (float)deg * EM1) : 2.0f / (float)Nn;
        int   n0 = 0, n1 = 0;
        float r0 = -INFINITY, r1 = -INFINITY;
        if (lane < deg)      { n0 = p.csrEn[e * EC + lane];      r0 = p.rowv[n0]; }
        if (lane + 64 < deg) { n1 = p.csrEn[e * EC + lane + 64]; r1 = p.rowv[n1]; }
        const float m  = wave_max64(fmaxf(r0, r1));
        const float e0 = (lane < deg)      ? expf(r0 - m) : 0.f;
        const float e1 = (lane + 64 < deg) ? expf(r1 - m) : 0.f;
        const float Z  = wave_sum64(e0 + e1);
        const float inv = deg ? 1.0f / Z : 0.f;
        const float base = EM1 * ue;
        if (lane < deg) {
            const float sv = fmaf(e0, inv, base);
            sm.e.sN[w][lane] = n0; sm.e.sS[w][lane] = sv;
            p.Sval[e * EC + lane] = sv;
            atomicAdd(&p.wsArr[n0], ue * sv);
        }
        if (lane + 64 < deg) {
            const float sv = fmaf(e1, inv, base);
            sm.e.sN[w][lane + 64] = n1; sm.e.sS[w][lane + 64] = sv;
            p.Sval[e * EC + lane + 64] = sv;
            atomicAdd(&p.wsArr[n1], ue * sv);
        }
        const float2 cw = *(const float2*)&p.csxw[lane * 2];
        const float2 c4 = *(const float2*)&p.csx4[lane * 2];
        float2 aE = make_float2(ue * cw.x, ue * cw.y);
        float2 aG = make_float2(ue * c4.x, ue * c4.y);
        const unsigned* x4u = (const unsigned*)p.x4b;
        const unsigned* xwu = (const unsigned*)p.xwb;
        int j = 0;
        for (; j + 8 <= deg; j += 8) {
            int ai[8]; float bi[8]; unsigned tu[8], fu[8];
#pragma unroll
            for (int k = 0; k < 8; ++k) { ai[k] = sm.e.sN[w][j+k]; bi[k] = sm.e.sS[w][j+k]; }
#pragma unroll
            for (int k = 0; k < 8; ++k) {
                tu[k] = xwu[(size_t)ai[k] * 64 + lane];
                fu[k] = x4u[(size_t)ai[k] * 64 + lane];
            }
#pragma unroll
            for (int k = 0; k < 8; ++k) {
                const float2 tv = unpackbf2(tu[k]);
                const float2 fv = unpackbf2(fu[k]);
                aE.x = fmaf(bi[k], tv.x, aE.x); aE.y = fmaf(bi[k], tv.y, aE.y);
                aG.x = fmaf(bi[k], fv.x, aG.x); aG.y = fmaf(bi[k], fv.y, aG.y);
            }
        }
        for (; j < deg; ++j) {
            const int   a = sm.e.sN[w][j];
            const float b = sm.e.sS[w][j];
            const float2 tv = unpackbf2(xwu[(size_t)a * 64 + lane]);
            const float2 fv = unpackbf2(x4u[(size_t)a * 64 + lane]);
            aE.x = fmaf(b, tv.x, aE.x); aE.y = fmaf(b, tv.y, aE.y);
            aG.x = fmaf(b, fv.x, aG.x); aG.y = fmaf(b, fv.y, aG.y);
        }
        p.e4b[(size_t)e * 64 + lane] = packbf2(aE.x, aE.y);
        p.G1b[(size_t)e * 64 + lane] = packbf2(aG.x, aG.y);
        if (lane == 0) sm.e.c2s[w] = ue * ue;
        __syncthreads();
        if (t == 0) {
            float s = 0.f;
#pragma unroll
            for (int k = 0; k < 16; ++k) s += sm.e.c2s[k];
            atomicAdd(p.c2g, s);
        }
    }
    grid.sync();

    // ===== P3: per-node softmax2 -> Tval, v[n]; weighted colsums ============
    {
        float2 vxa = {0,0}, twa = {0,0}, wsa = {0,0};
        const unsigned* x4u = (const unsigned*)p.x4b;
#pragma unroll
        for (int s = 0; s < 2; ++s) {
            const int n   = u + s * CWAV;
            const int deg = min(p.degN[n], NC);
            const float vn = deg ? 1.0f / ((float)Ee + (float)deg * EM1) : 2.0f / (float)Ee;
            const float2 xv = unpackbf2(x4u[(size_t)n * 64 + lane]);
            sm.r.sx[w][lane * 2 + 0] = xv.x;
            sm.r.sx[w][lane * 2 + 1] = xv.y;
            __builtin_amdgcn_s_waitcnt(0);   // LDS write visible to own wave
            int ej = 0, slot = 0;
            if (lane < deg) { ej = p.csrNe[n * NC + lane]; slot = p.csrNs[n * NC + lane]; }
            const uint4* er = (const uint4*)&p.e4b[(size_t)ej * 64];
            float dot = 0.f;
#pragma unroll
            for (int c0 = 0; c0 < 16; c0 += 8) {
                uint4 ev[8];
#pragma unroll
                for (int k = 0; k < 8; ++k) ev[k] = er[c0 + k];
#pragma unroll
                for (int k = 0; k < 8; ++k) {
                    const int base = (c0 + k) * 8;
                    const float2 e0 = unpackbf2(ev[k].x);
                    const float2 e1 = unpackbf2(ev[k].y);
                    const float2 e2 = unpackbf2(ev[k].z);
                    const float2 e3 = unpackbf2(ev[k].w);
                    dot = fmaf(e0.x, sm.r.sx[w][base + 0], dot);
                    dot = fmaf(e0.y, sm.r.sx[w][base + 1], dot);
                    dot = fmaf(e1.x, sm.r.sx[w][base + 2], dot);
                    dot = fmaf(e1.y, sm.r.sx[w][base + 3], dot);
                    dot = fmaf(e2.x, sm.r.sx[w][base + 4], dot);
                    dot = fmaf(e2.y, sm.r.sx[w][base + 5], dot);
                    dot = fmaf(e3.x, sm.r.sx[w][base + 6], dot);
                    dot = fmaf(e3.y, sm.r.sx[w][base + 7], dot);
                }
            }
            const float sj = (lane < deg) ? dot * TEMPR : -INFINITY;
            const float m  = wave_max64(sj);
            const float ex = (lane < deg) ? expf(sj - m) : 0.f;
            const float Z  = wave_sum64(ex);
            if (lane < deg) p.Tval[slot] = fmaf(EM1, vn, ex / Z);
            if (lane == 0) p.vArr[n] = vn;
            const float tw  = deg ? fmaf((float)deg * EM1, vn, 1.0f) : 0.f;
            const float wsn = p.wsArr[n];
            vxa.x = fmaf(vn,  xv.x, vxa.x); vxa.y = fmaf(vn,  xv.y, vxa.y);
            twa.x = fmaf(tw,  xv.x, twa.x); twa.y = fmaf(tw,  xv.y, twa.y);
            wsa.x = fmaf(wsn, xv.x, wsa.x); wsa.y = fmaf(wsn, xv.y, wsa.y);
        }
        __syncthreads();
        if (t < DOUT) { sm.r.a[t] = 0.f; sm.r.b[t] = 0.f; sm.r.c[t] = 0.f; }
        __syncthreads();
        atomicAdd(&sm.r.a[lane*2+0], vxa.x); atomicAdd(&sm.r.a[lane*2+1], vxa.y);
        atomicAdd(&sm.r.b[lane*2+0], twa.x); atomicAdd(&sm.r.b[lane*2+1], twa.y);
        atomicAdd(&sm.r.c[lane*2+0], wsa.x); atomicAdd(&sm.r.c[lane*2+1], wsa.y);
        __syncthreads();
        if (t < DOUT) {
            atomicAdd(&p.vxg[t],  sm.r.a[t]);
            atomicAdd(&p.twxg[t], sm.r.b[t]);
            atomicAdd(&p.wsxg[t], sm.r.c[t]);
        }
    }
    grid.sync();

    // ===== P4: per-edge G2 gather ===========================================
    {
        const int e   = u;
        const int deg = min(p.degE[e], EC);
        const unsigned* x4u = (const unsigned*)p.x4b;
        float2 acc = *(const float2*)&p.vxg[lane * 2];
        int j = 0;
        for (; j + 8 <= deg; j += 8) {
            int ai[8]; float bi[8]; unsigned fu[8];
#pragma unroll
            for (int k = 0; k < 8; ++k) {
                ai[k] = p.csrEn[e*EC+j+k]; bi[k] = p.Tval[e*EC+j+k];
            }
#pragma unroll
            for (int k = 0; k < 8; ++k) fu[k] = x4u[(size_t)ai[k] * 64 + lane];
#pragma unroll
            for (int k = 0; k < 8; ++k) {
                const float2 fv = unpackbf2(fu[k]);
                acc.x = fmaf(bi[k], fv.x, acc.x); acc.y = fmaf(bi[k], fv.y, acc.y);
            }
        }
        for (; j < deg; ++j) {
            const int   a = p.csrEn[e*EC+j];
            const float b = p.Tval[e*EC+j];
            const float2 fv = unpackbf2(x4u[(size_t)a * 64 + lane]);
            acc.x = fmaf(b, fv.x, acc.x); acc.y = fmaf(b, fv.y, acc.y);
        }
        p.G2b[(size_t)e * 64 + lane] = packbf2(acc.x, acc.y);
    }
    grid.sync();

    // ===== P5: final combine + elu ==========================================
    {
        const float c2 = *p.c2g;
        const float2 c4v = *(const float2*)&p.csx4[lane * 2];
        const float2 wsv = *(const float2*)&p.wsxg[lane * 2];
        const float2 vxv = *(const float2*)&p.vxg[lane * 2];
        const float2 twv = *(const float2*)&p.twxg[lane * 2];
#pragma unroll
        for (int s = 0; s < 2; ++s) {
            const int n   = u + s * CWAV;
            const int deg = min(p.degN[n], NC);
            const float vn = p.vArr[n];
            float2 acc;
            acc.x = fmaf(c2, c4v.x, wsv.x) + vn * fmaf((float)Ee, vxv.x, twv.x);
            acc.y = fmaf(c2, c4v.y, wsv.y) + vn * fmaf((float)Ee, vxv.y, twv.y);
            int j = 0;
            for (; j + 4 <= deg; j += 4) {
                int ei[4], si[4]; float sv[4], tv[4]; unsigned g1u[4], g2u[4];
#pragma unroll
                for (int k = 0; k < 4; ++k) {
                    ei[k] = p.csrNe[n*NC+j+k]; si[k] = p.csrNs[n*NC+j+k];
                }
#pragma unroll
                for (int k = 0; k < 4; ++k) {
                    sv[k] = p.Sval[si[k]]; tv[k] = p.Tval[si[k]];
                    g1u[k] = p.G1b[(size_t)ei[k] * 64 + lane];
                    g2u[k] = p.G2b[(size_t)ei[k] * 64 + lane];
                }
#pragma unroll
                for (int k = 0; k < 4; ++k) {
                    const float2 g1 = unpackbf2(g1u[k]);
                    const float2 g2 = unpackbf2(g2u[k]);
                    acc.x = fmaf(sv[k], g1.x, acc.x); acc.y = fmaf(sv[k], g1.y, acc.y);
                    acc.x = fmaf(tv[k], g2.x, acc.x); acc.y = fmaf(tv[k], g2.y, acc.y);
                }
            }
            for (; j < deg; ++j) {
                const int ea = p.csrNe[n*NC+j];
                const int sa = p.csrNs[n*NC+j];
                const float sva = p.Sval[sa], tva = p.Tval[sa];
                const float2 g1a = unpackbf2(p.G1b[(size_t)ea * 64 + lane]);
                const float2 g2a = unpackbf2(p.G2b[(size_t)ea * 64 + lane]);
                acc.x = fmaf(sva, g1a.x, acc.x); acc.y = fmaf(sva, g1a.y, acc.y);
                acc.x = fmaf(tva, g2a.x, acc.x); acc.y = fmaf(tva, g2a.y, acc.y);
            }
            acc.x = acc.x > 0.f ? acc.x : expm1f(acc.x);
            acc.y = acc.y > 0.f ? acc.y : expm1f(acc.y);
            *(float2*)&p.out[(size_t)n * DOUT + lane * 2] = acc;
        }
    }
}

// ===========================================================================
// Fallback pipeline — Round-7 proven kernels (used if cooperative launch fails)
// ===========================================================================
__global__ __launch_bounds__(256) void k_ww3(
    const float* __restrict__ W, const float* __restrict__ W2,
    const float* __restrict__ W3, const float* __restrict__ bias,
    short* __restrict__ W2T, short* __restrict__ WWT, float* __restrict__ bW3)
{
    const int b = blockIdx.x;
    const int t = threadIdx.x;
    if (b < 32) {
        __shared__ float sW[8][128];
        const int r0 = b * 8;
        for (int i = t; i < 1024; i += 256)
            sW[i >> 7][i & 127] = W[(size_t)(r0 + (i >> 7)) * DOUT + (i & 127)];
        __syncthreads();
        const int c  = t & 127;
        const int rh = (t >> 7) * 4;
        float acc[4] = {0.f, 0.f, 0.f, 0.f};
        for (int k = 0; k < 128; ++k) {
            const float w3 = W3[(size_t)k * DOUT + c];
#pragma unroll
            for (int i = 0; i < 4; ++i) acc[i] = fmaf(sW[rh + i][k], w3, acc[i]);
        }
#pragma unroll
        for (int i = 0; i < 4; ++i)
            WWT[(size_t)c * DIN + (r0 + rh + i)] = f2bf(acc[i]);
    } else if (b < 40) {
        const int k0 = (b - 32) * 32;
        for (int i = t; i < 32 * 128; i += 256) {
            const int k = k0 + (i >> 7);
            const int n = i & 127;
            W2T[(size_t)n * DIN + k] = f2bf(W2[(size_t)k * DOUT + n]);
        }
    } else {
        if (t < 128) {
            float acc = 0.f;
            for (int k = 0; k < 128; ++k)
                acc = fmaf(bias[k], W3[(size_t)k * DOUT + t], acc);
            bW3[t] = acc;
        }
    }
}

__global__ __launch_bounds__(256) void k_gemm1f(
    const float* __restrict__ x, const short* __restrict__ W2T,
    const short* __restrict__ WWT, const float* __restrict__ bW3,
    const float* __restrict__ q, const int* __restrict__ hidx,
    unsigned* __restrict__ bitmap, int* __restrict__ degE, int* __restrict__ degN,
    int* __restrict__ csrEn, int* __restrict__ csrNe, int* __restrict__ csrNs,
    short* __restrict__ x4b, short* __restrict__ xwb,
    float* __restrict__ rowv, float* __restrict__ csx4, float* __restrict__ csxw)
{
    __shared__ float s4[DOUT], sw[DOUT], srow[16];
    const int t    = threadIdx.x;
    const int lane = t & 63;
    const int wv   = t >> 6;
    const int n16  = lane & 15;
    const int quad = lane >> 4;
    const int r0   = blockIdx.x * 16;
    const int n0   = wv * 32;

    const unsigned gid = blockIdx.x * 256 + t;
    if (gid < NNZ) {
        const int n = hidx[gid];
        const int e = hidx[NNZ + gid];
        const unsigned word = (unsigned)n * (unsigned)Ee + (unsigned)e;
        const unsigned bit  = 1u << (word & 31u);
        const unsigned old  = atomicOr(&bitmap[word >> 5], bit);
        if (!(old & bit)) {
            const int pe = atomicAdd(&degE[e], 1);
            if (pe < EC) {
                csrEn[e * EC + pe] = n;
                const int pn = atomicAdd(&degN[n], 1);
                if (pn < NC) {
                    csrNe[n * NC + pn] = e;
                    csrNs[n * NC + pn] = e * EC + pe;
                }
            }
        }
    }

    f32x4 acc4[2], accw[2];
#pragma unroll
    for (int nt = 0; nt < 2; ++nt) {
        acc4[nt] = (f32x4){0.f, 0.f, 0.f, 0.f};
        accw[nt] = (f32x4){0.f, 0.f, 0.f, 0.f};
    }
#pragma unroll
    for (int k0 = 0; k0 < DIN; k0 += 32) {
        const int kb = k0 + quad * 8;
        const float4 xa = *(const float4*)&x[(size_t)(r0 + n16) * DIN + kb];
        const float4 xb = *(const float4*)&x[(size_t)(r0 + n16) * DIN + kb + 4];
        short8 af;
        af[0] = f2bf(xa.x); af[1] = f2bf(xa.y); af[2] = f2bf(xa.z); af[3] = f2bf(xa.w);
        af[4] = f2bf(xb.x); af[5] = f2bf(xb.y); af[6] = f2bf(xb.z); af[7] = f2bf(xb.w);
#pragma unroll
        for (int nt = 0; nt < 2; ++nt) {
            const int col = n0 + nt * 16 + n16;
            const short8 b4 = *(const short8*)&W2T[(size_t)col * DIN + kb];
            const short8 bw = *(const short8*)&WWT[(size_t)col * DIN + kb];
            acc4[nt] = __builtin_amdgcn_mfma_f32_16x16x32_bf16(af, b4, acc4[nt], 0, 0, 0);
            accw[nt] = __builtin_amdgcn_mfma_f32_16x16x32_bf16(af, bw, accw[nt], 0, 0, 0);
        }
    }
    float bwv[2], qv[2];
#pragma unroll
    for (int nt = 0; nt < 2; ++nt) {
        const int col = n0 + nt * 16 + n16;
        bwv[nt] = bW3[col];
        qv[nt]  = q[col];
    }
#pragma unroll
    for (int nt = 0; nt < 2; ++nt) {
        const int col = n0 + nt * 16 + n16;
#pragma unroll
        for (int reg = 0; reg < 4; ++reg) {
            const int row = r0 + quad * 4 + reg;
            x4b[(size_t)row * DOUT + col] = f2bf(acc4[nt][reg]);
            xwb[(size_t)row * DOUT + col] = f2bf(accw[nt][reg] + bwv[nt]);
        }
    }
    float pr[4];
#pragma unroll
    for (int reg = 0; reg < 4; ++reg)
        pr[reg] = qv[0] * acc4[0][reg] + qv[1] * acc4[1][reg];
#pragma unroll
    for (int m = 8; m; m >>= 1) {
#pragma unroll
        for (int reg = 0; reg < 4; ++reg) pr[reg] += __shfl_xor(pr[reg], m, 64);
    }
    if (t < 16) srow[t] = 0.f;
    if (t < DOUT) { s4[t] = 0.f; sw[t] = 0.f; }
    __syncthreads();
    if (n16 == 0) {
#pragma unroll
        for (int reg = 0; reg < 4; ++reg) atomicAdd(&srow[quad * 4 + reg], pr[reg]);
    }
#pragma unroll
    for (int nt = 0; nt < 2; ++nt) {
        const int col = n0 + nt * 16 + n16;
        const float c4s = acc4[nt][0] + acc4[nt][1] + acc4[nt][2] + acc4[nt][3];
        const float cws = accw[nt][0] + accw[nt][1] + accw[nt][2] + accw[nt][3]
                        + 4.f * bwv[nt];
        atomicAdd(&s4[col], c4s);
        atomicAdd(&sw[col], cws);
    }
    __syncthreads();
    if (t < 16) rowv[r0 + t] = srow[t] * TEMPR;
    if (t < DOUT) { atomicAdd(&csx4[t], s4[t]); atomicAdd(&csxw[t], sw[t]); }
}

__global__ __launch_bounds__(256) void k_edge1(
    const int* __restrict__ degE, const int* __restrict__ csrEn,
    const float* __restrict__ rowv,
    const float* __restrict__ csx4, const float* __restrict__ csxw,
    const unsigned* __restrict__ x4b, const unsigned* __restrict__ xwb,
    float* __restrict__ Sval, unsigned* __restrict__ e4b, unsigned* __restrict__ G1b,
    float* __restrict__ wsArr, float* __restrict__ c2g)
{
    __shared__ int   sN[4][EC];
    __shared__ float sS[4][EC];
    __shared__ float sC2[4];
    const int t    = threadIdx.x;
    const int w    = t >> 6;
    const int lane = t & 63;
    const int e    = blockIdx.x * 4 + w;
    const int deg  = min(degE[e], EC);
    const float ue = deg ? 1.0f / ((float)Nn + (float)deg * EM1) : 2.0f / (float)Nn;

    int   n0 = 0, n1 = 0;
    float r0 = -INFINITY, r1 = -INFINITY;
    if (lane < deg)      { n0 = csrEn[e * EC + lane];      r0 = rowv[n0]; }
    if (lane + 64 < deg) { n1 = csrEn[e * EC + lane + 64]; r1 = rowv[n1]; }
    const float m  = wave_max64(fmaxf(r0, r1));
    const float e0 = (lane < deg)      ? expf(r0 - m) : 0.f;
    const float e1 = (lane + 64 < deg) ? expf(r1 - m) : 0.f;
    const float Z  = wave_sum64(e0 + e1);
    const float inv = deg ? 1.0f / Z : 0.f;
    const float base = EM1 * ue;
    if (lane < deg) {
        const float sv = fmaf(e0, inv, base);
        sN[w][lane] = n0; sS[w][lane] = sv;
        Sval[e * EC + lane] = sv;
        atomicAdd(&wsArr[n0], ue * sv);
    }
    if (lane + 64 < deg) {
        const float sv = fmaf(e1, inv, base);
        sN[w][lane + 64] = n1; sS[w][lane + 64] = sv;
        Sval[e * EC + lane + 64] = sv;
        atomicAdd(&wsArr[n1], ue * sv);
    }
    const float2 cw = *(const float2*)&csxw[lane * 2];
    const float2 c4 = *(const float2*)&csx4[lane * 2];
    float2 aE = make_float2(ue * cw.x, ue * cw.y);
    float2 aG = make_float2(ue * c4.x, ue * c4.y);
    int j = 0;
    for (; j + 8 <= deg; j += 8) {
        int ai[8]; float bi[8]; unsigned tu[8], fu[8];
#pragma unroll
        for (int k = 0; k < 8; ++k) { ai[k] = sN[w][j+k]; bi[k] = sS[w][j+k]; }
#pragma unroll
        for (int k = 0; k < 8; ++k) {
            tu[k] = xwb[(size_t)ai[k] * 64 + lane];
            fu[k] = x4b[(size_t)ai[k] * 64 + lane];
        }
#pragma unroll
        for (int k = 0; k < 8; ++k) {
            const float2 tv = unpackbf2(tu[k]);
            const float2 fv = unpackbf2(fu[k]);
            aE.x = fmaf(bi[k], tv.x, aE.x); aE.y = fmaf(bi[k], tv.y, aE.y);
            aG.x = fmaf(bi[k], fv.x, aG.x); aG.y = fmaf(bi[k], fv.y, aG.y);
        }
    }
    for (; j < deg; ++j) {
        const int   a = sN[w][j];
        const float b = sS[w][j];
        const float2 tv = unpackbf2(xwb[(size_t)a * 64 + lane]);
        const float2 fv = unpackbf2(x4b[(size_t)a * 64 + lane]);
        aE.x = fmaf(b, tv.x, aE.x); aE.y = fmaf(b, tv.y, aE.y);
        aG.x = fmaf(b, fv.x, aG.x); aG.y = fmaf(b, fv.y, aG.y);
    }
    e4b[(size_t)e * 64 + lane] = packbf2(aE.x, aE.y);
    G1b[(size_t)e * 64 + lane] = packbf2(aG.x, aG.y);

    if (lane == 0) sC2[w] = ue * ue;
    __syncthreads();
    if (t == 0) atomicAdd(c2g, sC2[0] + sC2[1] + sC2[2] + sC2[3]);
}

__global__ __launch_bounds__(256) void k_node2(
    const int* __restrict__ degN, const int* __restrict__ csrNe,
    const int* __restrict__ csrNs, const unsigned* __restrict__ x4b,
    const unsigned* __restrict__ e4b, const float* __restrict__ wsArr,
    float* __restrict__ Tval, float* __restrict__ vArr,
    float* __restrict__ vxg, float* __restrict__ twxg, float* __restrict__ wsxg)
{
    __shared__ float sx[4][DOUT];
    __shared__ float sVX[DOUT], sTX[DOUT], sWX[DOUT];
    const int t    = threadIdx.x;
    const int w    = t >> 6;
    const int lane = t & 63;

    float2 vxa = {0,0}, twa = {0,0}, wsa = {0,0};
#pragma unroll
    for (int s = 0; s < 2; ++s) {
        const int n   = blockIdx.x * 8 + w * 2 + s;
        const int deg = min(degN[n], NC);
        const float vn = deg ? 1.0f / ((float)Ee + (float)deg * EM1) : 2.0f / (float)Ee;
        const float2 xv = unpackbf2(x4b[(size_t)n * 64 + lane]);
        __syncthreads();
        sx[w][lane * 2 + 0] = xv.x;
        sx[w][lane * 2 + 1] = xv.y;
        __syncthreads();
        int ej = 0, slot = 0;
        if (lane < deg) { ej = csrNe[n * NC + lane]; slot = csrNs[n * NC + lane]; }
        const uint4* er = (const uint4*)&e4b[(size_t)ej * 64];
        float dot = 0.f;
#pragma unroll
        for (int c0 = 0; c0 < 16; c0 += 8) {
            uint4 ev[8];
#pragma unroll
            for (int k = 0; k < 8; ++k) ev[k] = er[c0 + k];
#pragma unroll
            for (int k = 0; k < 8; ++k) {
                const int base = (c0 + k) * 8;
                const float2 e0 = unpackbf2(ev[k].x);
                const float2 e1 = unpackbf2(ev[k].y);
                const float2 e2 = unpackbf2(ev[k].z);
                const float2 e3 = unpackbf2(ev[k].w);
                dot = fmaf(e0.x, sx[w][base + 0], dot);
                dot = fmaf(e0.y, sx[w][base + 1], dot);
                dot = fmaf(e1.x, sx[w][base + 2], dot);
                dot = fmaf(e1.y, sx[w][base + 3], dot);
                dot = fmaf(e2.x, sx[w][base + 4], dot);
                dot = fmaf(e2.y, sx[w][base + 5], dot);
                dot = fmaf(e3.x, sx[w][base + 6], dot);
                dot = fmaf(e3.y, sx[w][base + 7], dot);
            }
        }
        const float sj = (lane < deg) ? dot * TEMPR : -INFINITY;
        const float m  = wave_max64(sj);
        const float ex = (lane < deg) ? expf(sj - m) : 0.f;
        const float Z  = wave_sum64(ex);
        if (lane < deg) Tval[slot] = fmaf(EM1, vn, ex / Z);
        if (lane == 0) vArr[n] = vn;
        const float tw  = deg ? fmaf((float)deg * EM1, vn, 1.0f) : 0.f;
        const float wsn = wsArr[n];
        vxa.x = fmaf(vn,  xv.x, vxa.x); vxa.y = fmaf(vn,  xv.y, vxa.y);
        twa.x = fmaf(tw,  xv.x, twa.x); twa.y = fmaf(tw,  xv.y, twa.y);
        wsa.x = fmaf(wsn, xv.x, wsa.x); wsa.y = fmaf(wsn, xv.y, wsa.y);
    }
    __syncthreads();
    if (t < DOUT) { sVX[t] = 0.f; sTX[t] = 0.f; sWX[t] = 0.f; }
    __syncthreads();
    atomicAdd(&sVX[lane*2+0], vxa.x); atomicAdd(&sVX[lane*2+1], vxa.y);
    atomicAdd(&sTX[lane*2+0], twa.x); atomicAdd(&sTX[lane*2+1], twa.y);
    atomicAdd(&sWX[lane*2+0], wsa.x); atomicAdd(&sWX[lane*2+1], wsa.y);
    __syncthreads();
    if (t < DOUT) {
        atomicAdd(&vxg[t],  sVX[t]);
        atomicAdd(&twxg[t], sTX[t]);
        atomicAdd(&wsxg[t], sWX[t]);
    }
}

__global__ __launch_bounds__(256) void k_g2(
    const int* __restrict__ degE, const int* __restrict__ csrEn,
    const float* __restrict__ Tval, const float* __restrict__ vxg,
    const unsigned* __restrict__ x4b, unsigned* __restrict__ G2b)
{
    const int t    = threadIdx.x;
    const int w    = t >> 6;
    const int lane = t & 63;
    const int e    = blockIdx.x * 4 + w;
    const int deg  = min(degE[e], EC);
    float2 acc = *(const float2*)&vxg[lane * 2];
    int j = 0;
    for (; j + 8 <= deg; j += 8) {
        int ai[8]; float bi[8]; unsigned fu[8];
#pragma unroll
        for (int k = 0; k < 8; ++k) { ai[k] = csrEn[e*EC+j+k]; bi[k] = Tval[e*EC+j+k]; }
#pragma unroll
        for (int k = 0; k < 8; ++k)
            fu[k] = x4b[(size_t)ai[k] * 64 + lane];
#pragma unroll
        for (int k = 0; k < 8; ++k) {
            const float2 fv = unpackbf2(fu[k]);
            acc.x = fmaf(bi[k], fv.x, acc.x); acc.y = fmaf(bi[k], fv.y, acc.y);
        }
    }
    for (; j < deg; ++j) {
        const int   a = csrEn[e*EC+j];
        const float b = Tval[e*EC+j];
        const float2 fv = unpackbf2(x4b[(size_t)a * 64 + lane]);
        acc.x = fmaf(b, fv.x, acc.x); acc.y = fmaf(b, fv.y, acc.y);
    }
    G2b[(size_t)e * 64 + lane] = packbf2(acc.x, acc.y);
}

__global__ __launch_bounds__(256) void k_final(
    const int* __restrict__ degN, const int* __restrict__ csrNe,
    const int* __restrict__ csrNs, const float* __restrict__ Sval,
    const float* __restrict__ Tval, const float* __restrict__ vArr,
    const float* __restrict__ c2g, const float* __restrict__ csx4,
    const float* __restrict__ wsxg, const float* __restrict__ vxg,
    const float* __restrict__ twxg,
    const unsigned* __restrict__ G1b, const unsigned* __restrict__ G2b,
    float* __restrict__ out)
{
    const int t    = threadIdx.x;
    const int w    = t >> 6;
    const int lane = t & 63;
    const int n    = blockIdx.x * 4 + w;
    const int deg  = min(degN[n], NC);
    const float vn = vArr[n];
    const float c2 = *c2g;
    const float2 c4v = *(const float2*)&csx4[lane * 2];
    const float2 wsv = *(const float2*)&wsxg[lane * 2];
    const float2 vxv = *(const float2*)&vxg[lane * 2];
    const float2 twv = *(const float2*)&twxg[lane * 2];
    float2 acc;
    acc.x = fmaf(c2, c4v.x, wsv.x) + vn * fmaf((float)Ee, vxv.x, twv.x);
    acc.y = fmaf(c2, c4v.y, wsv.y) + vn * fmaf((float)Ee, vxv.y, twv.y);
    int j = 0;
    for (; j + 4 <= deg; j += 4) {
        int ei[4], si[4]; float sv[4], tv[4]; unsigned g1u[4], g2u[4];
#pragma unroll
        for (int k = 0; k < 4; ++k) {
            ei[k] = csrNe[n*NC+j+k]; si[k] = csrNs[n*NC+j+k];
        }
#pragma unroll
        for (int k = 0; k < 4; ++k) {
            sv[k] = Sval[si[k]]; tv[k] = Tval[si[k]];
            g1u[k] = G1b[(size_t)ei[k] * 64 + lane];
            g2u[k] = G2b[(size_t)ei[k] * 64 + lane];
        }
#pragma unroll
        for (int k = 0; k < 4; ++k) {
            const float2 g1 = unpackbf2(g1u[k]);
            const float2 g2 = unpackbf2(g2u[k]);
            acc.x = fmaf(sv[k], g1.x, acc.x); acc.y = fmaf(sv[k], g1.y, acc.y);
            acc.x = fmaf(tv[k], g2.x, acc.x); acc.y = fmaf(tv[k], g2.y, acc.y);
        }
    }
    for (; j < deg; ++j) {
        const int ea = csrNe[n*NC+j];
        const int sa = csrNs[n*NC+j];
        const float sva = Sval[sa], tva = Tval[sa];
        const float2 g1a = unpackbf2(G1b[(size_t)ea * 64 + lane]);
        const float2 g2a = unpackbf2(G2b[(size_t)ea * 64 + lane]);
        acc.x = fmaf(sva, g1a.x, acc.x); acc.y = fmaf(sva, g1a.y, acc.y);
        acc.x = fmaf(tva, g2a.x, acc.x); acc.y = fmaf(tva, g2a.y, acc.y);
    }
    acc.x = acc.x > 0.f ? acc.x : expm1f(acc.x);
    acc.y = acc.y > 0.f ? acc.y : expm1f(acc.y);
    *(float2*)&out[(size_t)n * DOUT + lane * 2] = acc;
}

// ---------------------------------------------------------------------------
extern "C" void kernel_launch(void* const* d_in, const int* in_sizes, int n_in,
                              void* d_out, int out_size, void* d_ws, size_t ws_size,
                              hipStream_t stream)
{
    Prm prm;
    prm.x    = (const float*)d_in[0];
    prm.W    = (const float*)d_in[1];
    prm.W2   = (const float*)d_in[2];
    prm.W3   = (const float*)d_in[3];
    prm.bias = (const float*)d_in[4];
    prm.q    = (const float*)d_in[5];
    prm.hidx = (const int*)d_in[6];
    prm.out  = (float*)d_out;

    char* wsp = (char*)d_ws;
    size_t o = 0;
    auto take = [&](size_t bytes) {
        size_t r = o; o += (bytes + 255) & ~(size_t)255; return r;
    };
    // --- zero-initialized region ---
    prm.bitmap = (unsigned*)(wsp + take((size_t)Nn * Ee / 8));   // 4 MB
    prm.degE   = (int*)  (wsp + take((size_t)Ee * 4));
    prm.degN   = (int*)  (wsp + take((size_t)Nn * 4));
    prm.wsArr  = (float*)(wsp + take((size_t)Nn * 4));
    prm.c2g    = (float*)(wsp + take(4));
    prm.csx4   = (float*)(wsp + take(DOUT * 4));
    prm.csxw   = (float*)(wsp + take(DOUT * 4));
    prm.vxg    = (float*)(wsp + take(DOUT * 4));
    prm.twxg   = (float*)(wsp + take(DOUT * 4));
    prm.wsxg   = (float*)(wsp + take(DOUT * 4));
    prm.zbase  = d_ws;
    const size_t zbytes = o;
    prm.zTotal16 = (unsigned)(zbytes / 16);
    // --- fully-overwritten scratch ---
    prm.x4b   = (short*)(wsp + take((size_t)Nn * DOUT * 2));
    prm.xwb   = (short*)(wsp + take((size_t)Nn * DOUT * 2));
    prm.rowv  = (float*)(wsp + take((size_t)Nn * 4));
    prm.vArr  = (float*)(wsp + take((size_t)Nn * 4));
    prm.csrEn = (int*)  (wsp + take((size_t)Ee * EC * 4));
    prm.Sval  = (float*)(wsp + take((size_t)Ee * EC * 4));
    prm.Tval  = (float*)(wsp + take((size_t)Ee * EC * 4));
    prm.csrNe = (int*)  (wsp + take((size_t)Nn * NC * 4));
    prm.csrNs = (int*)  (wsp + take((size_t)Nn * NC * 4));
    prm.e4b   = (unsigned*)(wsp + take((size_t)Ee * DOUT * 2));
    prm.G1b   = (unsigned*)(wsp + take((size_t)Ee * DOUT * 2));
    prm.G2b   = (unsigned*)(wsp + take((size_t)Ee * DOUT * 2));
    prm.W2T   = (short*)(wsp + take((size_t)DOUT * DIN * 2));
    prm.WWT   = (short*)(wsp + take((size_t)DOUT * DIN * 2));
    prm.bW3   = (float*)(wsp + take(DOUT * 4));
    (void)ws_size; (void)in_sizes; (void)n_in; (void)out_size;

    void* args[] = { &prm };
    hipError_t err = hipLaunchCooperativeKernel((void*)mega2, dim3(CBLK),
                                                dim3(CTHR), args, 0, stream);
    if (err != hipSuccess) {
        // Fallback: proven Round-7 pipeline.
        hipMemsetAsync(d_ws, 0, zbytes, stream);
        k_ww3   <<<41,      256, 0, stream>>>(prm.x ? prm.W : prm.W, prm.W2, prm.W3,
                                              prm.bias, prm.W2T, prm.WWT, prm.bW3);
        k_gemm1f<<<Nn / 16, 256, 0, stream>>>(prm.x, prm.W2T, prm.WWT, prm.bW3,
                                              prm.q, prm.hidx, prm.bitmap, prm.degE,
                                              prm.degN, prm.csrEn, prm.csrNe, prm.csrNs,
                                              prm.x4b, prm.xwb, prm.rowv,
                                              prm.csx4, prm.csxw);
        k_edge1 <<<Ee / 4,  256, 0, stream>>>(prm.degE, prm.csrEn, prm.rowv,
                                              prm.csx4, prm.csxw,
                                              (const unsigned*)prm.x4b,
                                              (const unsigned*)prm.xwb,
                                              prm.Sval, prm.e4b, prm.G1b,
                                              prm.wsArr, prm.c2g);
        k_node2 <<<Nn / 8,  256, 0, stream>>>(prm.degN, prm.csrNe, prm.csrNs,
                                              (const unsigned*)prm.x4b, prm.e4b,
                                              prm.wsArr, prm.Tval, prm.vArr,
                                              prm.vxg, prm.twxg, prm.wsxg);
        k_g2    <<<Ee / 4,  256, 0, stream>>>(prm.degE, prm.csrEn, prm.Tval, prm.vxg,
                                              (const unsigned*)prm.x4b, prm.G2b);
        k_final <<<Nn / 4,  256, 0, stream>>>(prm.degN, prm.csrNe, prm.csrNs,
                                              prm.Sval, prm.Tval, prm.vArr,
                                              prm.c2g, prm.csx4, prm.wsxg, prm.vxg,
                                              prm.twxg, prm.G1b, prm.G2b, prm.out);
    }
}

// Round 9
// 182.083 us; speedup vs baseline: 1.7625x; 1.7625x over previous
//
#include <hip/hip_runtime.h>
#include <math.h>

// Problem constants (match reference)
constexpr int Nn   = 8192;
constexpr int Ee   = 4096;
constexpr int DIN  = 256;
constexpr int DOUT = 128;
constexpr int NNZ  = 65536;
constexpr int EC   = 96;   // capacity: nodes per edge (deg ~ Poisson(16))
constexpr int NC   = 48;   // capacity: edges per node (deg ~ Poisson(8))

#define TEMPR 0.08838834764831845f   // 1/sqrt(128)
#define EM1   1.7182818284590452f    // e - 1

typedef __attribute__((ext_vector_type(8))) short short8;
typedef __attribute__((ext_vector_type(4))) float f32x4;

static __device__ __forceinline__ float wave_sum64(float v) {
#pragma unroll
    for (int m = 32; m; m >>= 1) v += __shfl_xor(v, m, 64);
    return v;
}
static __device__ __forceinline__ float wave_max64(float v) {
#pragma unroll
    for (int m = 32; m; m >>= 1) v = fmaxf(v, __shfl_xor(v, m, 64));
    return v;
}
static __device__ __forceinline__ short f2bf(float f) {
    union { float f; unsigned u; } v; v.f = f;
    const unsigned r = (v.u + 0x7FFFu + ((v.u >> 16) & 1u)) >> 16;
    return (short)r;
}
static __device__ __forceinline__ unsigned packbf2(float a, float b) {
    return ((unsigned)(unsigned short)f2bf(a)) |
           (((unsigned)(unsigned short)f2bf(b)) << 16);
}
static __device__ __forceinline__ float2 unpackbf2(unsigned u) {
    union { unsigned u; float f; } lo, hi;
    lo.u = u << 16; hi.u = u & 0xFFFF0000u;
    return make_float2(lo.f, hi.f);
}

// ---------------------------------------------------------------------------
// K0: prologue (also zeroes the accumulator/bitmap region -> no memset node).
//  blocks 0..31  : WW3 = W @ W3 (256x128) -> transposed-bf16 WWT[c][r]
//  blocks 32..39 : W2 transpose-bf16  W2T[n][k]
//  block  40     : bW3 = bias @ W3 (fp32)
//  blocks 41..104: zero z-region (uint4 strided)
// ---------------------------------------------------------------------------
__global__ __launch_bounds__(256) void k_ww3(
    const float* __restrict__ W, const float* __restrict__ W2,
    const float* __restrict__ W3, const float* __restrict__ bias,
    short* __restrict__ W2T, short* __restrict__ WWT, float* __restrict__ bW3,
    uint4* __restrict__ zb, unsigned zTot16)
{
    const int b = blockIdx.x;
    const int t = threadIdx.x;
    if (b < 32) {
        __shared__ float sW[8][128];
        const int r0 = b * 8;
        for (int i = t; i < 1024; i += 256)
            sW[i >> 7][i & 127] = W[(size_t)(r0 + (i >> 7)) * DOUT + (i & 127)];
        __syncthreads();
        const int c  = t & 127;
        const int rh = (t >> 7) * 4;
        float acc[4] = {0.f, 0.f, 0.f, 0.f};
        for (int k = 0; k < 128; ++k) {
            const float w3 = W3[(size_t)k * DOUT + c];
#pragma unroll
            for (int i = 0; i < 4; ++i) acc[i] = fmaf(sW[rh + i][k], w3, acc[i]);
        }
#pragma unroll
        for (int i = 0; i < 4; ++i)
            WWT[(size_t)c * DIN + (r0 + rh + i)] = f2bf(acc[i]);
    } else if (b < 40) {
        const int k0 = (b - 32) * 32;
        for (int i = t; i < 32 * 128; i += 256) {
            const int k = k0 + (i >> 7);
            const int n = i & 127;
            W2T[(size_t)n * DIN + k] = f2bf(W2[(size_t)k * DOUT + n]);
        }
    } else if (b == 40) {
        if (t < 128) {
            float acc = 0.f;
            for (int k = 0; k < 128; ++k)
                acc = fmaf(bias[k], W3[(size_t)k * DOUT + t], acc);
            bW3[t] = acc;
        }
    } else {
        uint4 z; z.x = z.y = z.z = z.w = 0u;
        for (unsigned i = (unsigned)(b - 41) * 256u + t; i < zTot16;
             i += 64u * 256u)
            zb[i] = z;
    }
}

// ---------------------------------------------------------------------------
// K1: MFMA GEMM  x4 = x@W2, xw = x@WW3 + bW3  -> bf16 arrays x4b/xwb
//     + CSR build + fp32 epilogues (rowv from exact accumulators, colsums).
// ---------------------------------------------------------------------------
__global__ __launch_bounds__(256) void k_gemm1f(
    const float* __restrict__ x, const short* __restrict__ W2T,
    const short* __restrict__ WWT, const float* __restrict__ bW3,
    const float* __restrict__ q, const int* __restrict__ hidx,
    unsigned* __restrict__ bitmap, int* __restrict__ degE, int* __restrict__ degN,
    int* __restrict__ csrEn, int* __restrict__ csrNe, int* __restrict__ csrNs,
    short* __restrict__ x4b, short* __restrict__ xwb,
    float* __restrict__ rowv, float* __restrict__ csx4, float* __restrict__ csxw)
{
    __shared__ float s4[DOUT], sw[DOUT], srow[16];
    const int t    = threadIdx.x;
    const int lane = t & 63;
    const int wv   = t >> 6;
    const int n16  = lane & 15;
    const int quad = lane >> 4;
    const int r0   = blockIdx.x * 16;
    const int n0   = wv * 32;

    // ---- CSR build ----
    const unsigned gid = blockIdx.x * 256 + t;
    if (gid < NNZ) {
        const int n = hidx[gid];
        const int e = hidx[NNZ + gid];
        const unsigned word = (unsigned)n * (unsigned)Ee + (unsigned)e;
        const unsigned bit  = 1u << (word & 31u);
        const unsigned old  = atomicOr(&bitmap[word >> 5], bit);
        if (!(old & bit)) {
            const int pe = atomicAdd(&degE[e], 1);
            if (pe < EC) {
                csrEn[e * EC + pe] = n;
                const int pn = atomicAdd(&degN[n], 1);
                if (pn < NC) {
                    csrNe[n * NC + pn] = e;
                    csrNs[n * NC + pn] = e * EC + pe;
                }
            }
        }
    }

    // ---- MFMA main loop ----
    f32x4 acc4[2], accw[2];
#pragma unroll
    for (int nt = 0; nt < 2; ++nt) {
        acc4[nt] = (f32x4){0.f, 0.f, 0.f, 0.f};
        accw[nt] = (f32x4){0.f, 0.f, 0.f, 0.f};
    }
#pragma unroll
    for (int k0 = 0; k0 < DIN; k0 += 32) {
        const int kb = k0 + quad * 8;
        const float4 xa = *(const float4*)&x[(size_t)(r0 + n16) * DIN + kb];
        const float4 xb = *(const float4*)&x[(size_t)(r0 + n16) * DIN + kb + 4];
        short8 af;
        af[0] = f2bf(xa.x); af[1] = f2bf(xa.y); af[2] = f2bf(xa.z); af[3] = f2bf(xa.w);
        af[4] = f2bf(xb.x); af[5] = f2bf(xb.y); af[6] = f2bf(xb.z); af[7] = f2bf(xb.w);
#pragma unroll
        for (int nt = 0; nt < 2; ++nt) {
            const int col = n0 + nt * 16 + n16;
            const short8 b4 = *(const short8*)&W2T[(size_t)col * DIN + kb];
            const short8 bw = *(const short8*)&WWT[(size_t)col * DIN + kb];
            acc4[nt] = __builtin_amdgcn_mfma_f32_16x16x32_bf16(af, b4, acc4[nt], 0, 0, 0);
            accw[nt] = __builtin_amdgcn_mfma_f32_16x16x32_bf16(af, bw, accw[nt], 0, 0, 0);
        }
    }

    // ---- writeback (bf16) + epilogues (fp32) ----
    float bwv[2], qv[2];
#pragma unroll
    for (int nt = 0; nt < 2; ++nt) {
        const int col = n0 + nt * 16 + n16;
        bwv[nt] = bW3[col];
        qv[nt]  = q[col];
    }
#pragma unroll
    for (int nt = 0; nt < 2; ++nt) {
        const int col = n0 + nt * 16 + n16;
#pragma unroll
        for (int reg = 0; reg < 4; ++reg) {
            const int row = r0 + quad * 4 + reg;
            x4b[(size_t)row * DOUT + col] = f2bf(acc4[nt][reg]);
            xwb[(size_t)row * DOUT + col] = f2bf(accw[nt][reg] + bwv[nt]);
        }
    }
    float pr[4];
#pragma unroll
    for (int reg = 0; reg < 4; ++reg)
        pr[reg] = qv[0] * acc4[0][reg] + qv[1] * acc4[1][reg];
#pragma unroll
    for (int m = 8; m; m >>= 1) {
#pragma unroll
        for (int reg = 0; reg < 4; ++reg) pr[reg] += __shfl_xor(pr[reg], m, 64);
    }
    if (t < 16) srow[t] = 0.f;
    if (t < DOUT) { s4[t] = 0.f; sw[t] = 0.f; }
    __syncthreads();
    if (n16 == 0) {
#pragma unroll
        for (int reg = 0; reg < 4; ++reg) atomicAdd(&srow[quad * 4 + reg], pr[reg]);
    }
#pragma unroll
    for (int nt = 0; nt < 2; ++nt) {
        const int col = n0 + nt * 16 + n16;
        const float c4s = acc4[nt][0] + acc4[nt][1] + acc4[nt][2] + acc4[nt][3];
        const float cws = accw[nt][0] + accw[nt][1] + accw[nt][2] + accw[nt][3]
                        + 4.f * bwv[nt];
        atomicAdd(&s4[col], c4s);
        atomicAdd(&sw[col], cws);
    }
    __syncthreads();
    if (t < 16) rowv[r0 + t] = srow[t] * TEMPR;
    if (t < DOUT) { atomicAdd(&csx4[t], s4[t]); atomicAdd(&csxw[t], sw[t]); }
}

// ---------------------------------------------------------------------------
// K2: per-edge: softmax1 -> Sval + ws scatter + c2; bf16 gathers:
//     e4b = att1 @ xw,  G1b = att1 @ x4
// ---------------------------------------------------------------------------
__global__ __launch_bounds__(256) void k_edge1(
    const int* __restrict__ degE, const int* __restrict__ csrEn,
    const float* __restrict__ rowv,
    const float* __restrict__ csx4, const float* __restrict__ csxw,
    const unsigned* __restrict__ x4b, const unsigned* __restrict__ xwb,
    float* __restrict__ Sval, unsigned* __restrict__ e4b, unsigned* __restrict__ G1b,
    float* __restrict__ wsArr, float* __restrict__ c2g)
{
    __shared__ int   sN[4][EC];
    __shared__ float sS[4][EC];
    __shared__ float sC2[4];
    const int t    = threadIdx.x;
    const int w    = t >> 6;
    const int lane = t & 63;
    const int e    = blockIdx.x * 4 + w;
    const int deg  = min(degE[e], EC);
    const float ue = deg ? 1.0f / ((float)Nn + (float)deg * EM1) : 2.0f / (float)Nn;

    int   n0 = 0, n1 = 0;
    float r0 = -INFINITY, r1 = -INFINITY;
    if (lane < deg)      { n0 = csrEn[e * EC + lane];      r0 = rowv[n0]; }
    if (lane + 64 < deg) { n1 = csrEn[e * EC + lane + 64]; r1 = rowv[n1]; }
    const float m  = wave_max64(fmaxf(r0, r1));
    const float e0 = (lane < deg)      ? expf(r0 - m) : 0.f;
    const float e1 = (lane + 64 < deg) ? expf(r1 - m) : 0.f;
    const float Z  = wave_sum64(e0 + e1);
    const float inv = deg ? 1.0f / Z : 0.f;
    const float base = EM1 * ue;
    if (lane < deg) {
        const float sv = fmaf(e0, inv, base);
        sN[w][lane] = n0; sS[w][lane] = sv;
        Sval[e * EC + lane] = sv;
        atomicAdd(&wsArr[n0], ue * sv);
    }
    if (lane + 64 < deg) {
        const float sv = fmaf(e1, inv, base);
        sN[w][lane + 64] = n1; sS[w][lane + 64] = sv;
        Sval[e * EC + lane + 64] = sv;
        atomicAdd(&wsArr[n1], ue * sv);
    }

    const float2 cw = *(const float2*)&csxw[lane * 2];
    const float2 c4 = *(const float2*)&csx4[lane * 2];
    float2 aE = make_float2(ue * cw.x, ue * cw.y);
    float2 aG = make_float2(ue * c4.x, ue * c4.y);
    int j = 0;
    for (; j + 8 <= deg; j += 8) {
        int ai[8]; float bi[8]; unsigned tu[8], fu[8];
#pragma unroll
        for (int k = 0; k < 8; ++k) { ai[k] = sN[w][j+k]; bi[k] = sS[w][j+k]; }
#pragma unroll
        for (int k = 0; k < 8; ++k) {
            tu[k] = xwb[(size_t)ai[k] * 64 + lane];
            fu[k] = x4b[(size_t)ai[k] * 64 + lane];
        }
#pragma unroll
        for (int k = 0; k < 8; ++k) {
            const float2 tv = unpackbf2(tu[k]);
            const float2 fv = unpackbf2(fu[k]);
            aE.x = fmaf(bi[k], tv.x, aE.x); aE.y = fmaf(bi[k], tv.y, aE.y);
            aG.x = fmaf(bi[k], fv.x, aG.x); aG.y = fmaf(bi[k], fv.y, aG.y);
        }
    }
    for (; j < deg; ++j) {
        const int   a = sN[w][j];
        const float b = sS[w][j];
        const float2 tv = unpackbf2(xwb[(size_t)a * 64 + lane]);
        const float2 fv = unpackbf2(x4b[(size_t)a * 64 + lane]);
        aE.x = fmaf(b, tv.x, aE.x); aE.y = fmaf(b, tv.y, aE.y);
        aG.x = fmaf(b, fv.x, aG.x); aG.y = fmaf(b, fv.y, aG.y);
    }
    e4b[(size_t)e * 64 + lane] = packbf2(aE.x, aE.y);
    G1b[(size_t)e * 64 + lane] = packbf2(aG.x, aG.y);

    if (lane == 0) sC2[w] = ue * ue;
    __syncthreads();
    if (t == 0) atomicAdd(c2g, sC2[0] + sC2[1] + sC2[2] + sC2[3]);
}

// ---------------------------------------------------------------------------
// K3: per-node softmax2 (lane-per-edge streaming dots over bf16 e4b rows)
//     -> Tval, v[n]; weighted colsum epilogues. Per-wave LDS staging, no
//     cross-wave syncs in the node loop (sx[w] is wave-exclusive; per-wave
//     DS ops are ordered).
// ---------------------------------------------------------------------------
__global__ __launch_bounds__(256) void k_node2(
    const int* __restrict__ degN, const int* __restrict__ csrNe,
    const int* __restrict__ csrNs, const unsigned* __restrict__ x4b,
    const unsigned* __restrict__ e4b, const float* __restrict__ wsArr,
    float* __restrict__ Tval, float* __restrict__ vArr,
    float* __restrict__ vxg, float* __restrict__ twxg, float* __restrict__ wsxg)
{
    __shared__ float sx[4][DOUT];
    __shared__ float sVX[DOUT], sTX[DOUT], sWX[DOUT];
    const int t    = threadIdx.x;
    const int w    = t >> 6;
    const int lane = t & 63;

    float2 vxa = {0,0}, twa = {0,0}, wsa = {0,0};
#pragma unroll
    for (int s = 0; s < 2; ++s) {
        const int n   = blockIdx.x * 8 + w * 2 + s;
        const int deg = min(degN[n], NC);
        const float vn = deg ? 1.0f / ((float)Ee + (float)deg * EM1) : 2.0f / (float)Ee;
        const float2 xv = unpackbf2(x4b[(size_t)n * 64 + lane]);
        sx[w][lane * 2 + 0] = xv.x;
        sx[w][lane * 2 + 1] = xv.y;
        __builtin_amdgcn_s_waitcnt(0);     // own-wave LDS writes visible
        int ej = 0, slot = 0;
        if (lane < deg) { ej = csrNe[n * NC + lane]; slot = csrNs[n * NC + lane]; }
        const uint4* er = (const uint4*)&e4b[(size_t)ej * 64];
        float dot = 0.f;
#pragma unroll
        for (int c0 = 0; c0 < 16; c0 += 8) {
            uint4 ev[8];
#pragma unroll
            for (int k = 0; k < 8; ++k) ev[k] = er[c0 + k];
#pragma unroll
            for (int k = 0; k < 8; ++k) {
                const int base = (c0 + k) * 8;
                const float2 e0 = unpackbf2(ev[k].x);
                const float2 e1 = unpackbf2(ev[k].y);
                const float2 e2 = unpackbf2(ev[k].z);
                const float2 e3 = unpackbf2(ev[k].w);
                dot = fmaf(e0.x, sx[w][base + 0], dot);
                dot = fmaf(e0.y, sx[w][base + 1], dot);
                dot = fmaf(e1.x, sx[w][base + 2], dot);
                dot = fmaf(e1.y, sx[w][base + 3], dot);
                dot = fmaf(e2.x, sx[w][base + 4], dot);
                dot = fmaf(e2.y, sx[w][base + 5], dot);
                dot = fmaf(e3.x, sx[w][base + 6], dot);
                dot = fmaf(e3.y, sx[w][base + 7], dot);
            }
        }
        const float sj = (lane < deg) ? dot * TEMPR : -INFINITY;
        const float m  = wave_max64(sj);
        const float ex = (lane < deg) ? expf(sj - m) : 0.f;
        const float Z  = wave_sum64(ex);
        if (lane < deg) Tval[slot] = fmaf(EM1, vn, ex / Z);
        if (lane == 0) vArr[n] = vn;
        const float tw  = deg ? fmaf((float)deg * EM1, vn, 1.0f) : 0.f;
        const float wsn = wsArr[n];
        vxa.x = fmaf(vn,  xv.x, vxa.x); vxa.y = fmaf(vn,  xv.y, vxa.y);
        twa.x = fmaf(tw,  xv.x, twa.x); twa.y = fmaf(tw,  xv.y, twa.y);
        wsa.x = fmaf(wsn, xv.x, wsa.x); wsa.y = fmaf(wsn, xv.y, wsa.y);
    }
    __syncthreads();
    if (t < DOUT) { sVX[t] = 0.f; sTX[t] = 0.f; sWX[t] = 0.f; }
    __syncthreads();
    atomicAdd(&sVX[lane*2+0], vxa.x); atomicAdd(&sVX[lane*2+1], vxa.y);
    atomicAdd(&sTX[lane*2+0], twa.x); atomicAdd(&sTX[lane*2+1], twa.y);
    atomicAdd(&sWX[lane*2+0], wsa.x); atomicAdd(&sWX[lane*2+1], wsa.y);
    __syncthreads();
    if (t < DOUT) {
        atomicAdd(&vxg[t],  sVX[t]);
        atomicAdd(&twxg[t], sTX[t]);
        atomicAdd(&wsxg[t], sWX[t]);
    }
}

// ---------------------------------------------------------------------------
// K4: per-edge: G2b[e] = vx + sum_{n in e} T[e,n] * x4[n]   (bf16 gather)
// ---------------------------------------------------------------------------
__global__ __launch_bounds__(256) void k_g2(
    const int* __restrict__ degE, const int* __restrict__ csrEn,
    const float* __restrict__ Tval, const float* __restrict__ vxg,
    const unsigned* __restrict__ x4b, unsigned* __restrict__ G2b)
{
    const int t    = threadIdx.x;
    const int w    = t >> 6;
    const int lane = t & 63;
    const int e    = blockIdx.x * 4 + w;
    const int deg  = min(degE[e], EC);
    float2 acc = *(const float2*)&vxg[lane * 2];
    int j = 0;
    for (; j + 8 <= deg; j += 8) {
        int ai[8]; float bi[8]; unsigned fu[8];
#pragma unroll
        for (int k = 0; k < 8; ++k) { ai[k] = csrEn[e*EC+j+k]; bi[k] = Tval[e*EC+j+k]; }
#pragma unroll
        for (int k = 0; k < 8; ++k)
            fu[k] = x4b[(size_t)ai[k] * 64 + lane];
#pragma unroll
        for (int k = 0; k < 8; ++k) {
            const float2 fv = unpackbf2(fu[k]);
            acc.x = fmaf(bi[k], fv.x, acc.x); acc.y = fmaf(bi[k], fv.y, acc.y);
        }
    }
    for (; j < deg; ++j) {
        const int   a = csrEn[e*EC+j];
        const float b = Tval[e*EC+j];
        const float2 fv = unpackbf2(x4b[(size_t)a * 64 + lane]);
        acc.x = fmaf(b, fv.x, acc.x); acc.y = fmaf(b, fv.y, acc.y);
    }
    G2b[(size_t)e * 64 + lane] = packbf2(acc.x, acc.y);
}

// ---------------------------------------------------------------------------
// K5: final per-node combine + elu  (bf16 gathers of G1b/G2b)
// ---------------------------------------------------------------------------
__global__ __launch_bounds__(256) void k_final(
    const int* __restrict__ degN, const int* __restrict__ csrNe,
    const int* __restrict__ csrNs, const float* __restrict__ Sval,
    const float* __restrict__ Tval, const float* __restrict__ vArr,
    const float* __restrict__ c2g, const float* __restrict__ csx4,
    const float* __restrict__ wsxg, const float* __restrict__ vxg,
    const float* __restrict__ twxg,
    const unsigned* __restrict__ G1b, const unsigned* __restrict__ G2b,
    float* __restrict__ out)
{
    const int t    = threadIdx.x;
    const int w    = t >> 6;
    const int lane = t & 63;
    const int n    = blockIdx.x * 4 + w;
    const int deg  = min(degN[n], NC);
    const float vn = vArr[n];
    const float c2 = *c2g;
    const float2 c4v = *(const float2*)&csx4[lane * 2];
    const float2 wsv = *(const float2*)&wsxg[lane * 2];
    const float2 vxv = *(const float2*)&vxg[lane * 2];
    const float2 twv = *(const float2*)&twxg[lane * 2];
    float2 acc;
    acc.x = fmaf(c2, c4v.x, wsv.x) + vn * fmaf((float)Ee, vxv.x, twv.x);
    acc.y = fmaf(c2, c4v.y, wsv.y) + vn * fmaf((float)Ee, vxv.y, twv.y);
    int j = 0;
    for (; j + 4 <= deg; j += 4) {
        int ei[4], si[4]; float sv[4], tv[4]; unsigned g1u[4], g2u[4];
#pragma unroll
        for (int k = 0; k < 4; ++k) {
            ei[k] = csrNe[n*NC+j+k]; si[k] = csrNs[n*NC+j+k];
        }
#pragma unroll
        for (int k = 0; k < 4; ++k) {
            sv[k] = Sval[si[k]]; tv[k] = Tval[si[k]];
            g1u[k] = G1b[(size_t)ei[k] * 64 + lane];
            g2u[k] = G2b[(size_t)ei[k] * 64 + lane];
        }
#pragma unroll
        for (int k = 0; k < 4; ++k) {
            const float2 g1 = unpackbf2(g1u[k]);
            const float2 g2 = unpackbf2(g2u[k]);
            acc.x = fmaf(sv[k], g1.x, acc.x); acc.y = fmaf(sv[k], g1.y, acc.y);
            acc.x = fmaf(tv[k], g2.x, acc.x); acc.y = fmaf(tv[k], g2.y, acc.y);
        }
    }
    for (; j < deg; ++j) {
        const int ea = csrNe[n*NC+j];
        const int sa = csrNs[n*NC+j];
        const float sva = Sval[sa], tva = Tval[sa];
        const float2 g1a = unpackbf2(G1b[(size_t)ea * 64 + lane]);
        const float2 g2a = unpackbf2(G2b[(size_t)ea * 64 + lane]);
        acc.x = fmaf(sva, g1a.x, acc.x); acc.y = fmaf(sva, g1a.y, acc.y);
        acc.x = fmaf(tva, g2a.x, acc.x); acc.y = fmaf(tva, g2a.y, acc.y);
    }
    acc.x = acc.x > 0.f ? acc.x : expm1f(acc.x);
    acc.y = acc.y > 0.f ? acc.y : expm1f(acc.y);
    *(float2*)&out[(size_t)n * DOUT + lane * 2] = acc;
}

// ---------------------------------------------------------------------------
extern "C" void kernel_launch(void* const* d_in, const int* in_sizes, int n_in,
                              void* d_out, int out_size, void* d_ws, size_t ws_size,
                              hipStream_t stream)
{
    const float* x    = (const float*)d_in[0];
    const float* W    = (const float*)d_in[1];
    const float* W2   = (const float*)d_in[2];
    const float* W3   = (const float*)d_in[3];
    const float* bias = (const float*)d_in[4];
    const float* q    = (const float*)d_in[5];
    const int*   hidx = (const int*)d_in[6];
    float* out = (float*)d_out;

    char* wsp = (char*)d_ws;
    size_t o = 0;
    auto take = [&](size_t bytes) {
        size_t r = o; o += (bytes + 255) & ~(size_t)255; return r;
    };
    // --- zero-initialized region (zeroed by k_ww3 blocks 41..104) ---
    unsigned* bitmap = (unsigned*)(wsp + take((size_t)Nn * Ee / 8));   // 4 MB
    int*   degE  = (int*)  (wsp + take((size_t)Ee * 4));
    int*   degN  = (int*)  (wsp + take((size_t)Nn * 4));
    float* wsArr = (float*)(wsp + take((size_t)Nn * 4));
    float* c2g   = (float*)(wsp + take(4));
    float* csx4  = (float*)(wsp + take(DOUT * 4));
    float* csxw  = (float*)(wsp + take(DOUT * 4));
    float* vxg   = (float*)(wsp + take(DOUT * 4));
    float* twxg  = (float*)(wsp + take(DOUT * 4));
    float* wsxg  = (float*)(wsp + take(DOUT * 4));
    const size_t zbytes = o;
    // --- fully-overwritten scratch ---
    short* x4b   = (short*)(wsp + take((size_t)Nn * DOUT * 2));   // bf16
    short* xwb   = (short*)(wsp + take((size_t)Nn * DOUT * 2));   // bf16
    float* rowv  = (float*)(wsp + take((size_t)Nn * 4));
    float* vArr  = (float*)(wsp + take((size_t)Nn * 4));
    int*   csrEn = (int*)  (wsp + take((size_t)Ee * EC * 4));
    float* Sval  = (float*)(wsp + take((size_t)Ee * EC * 4));
    float* Tval  = (float*)(wsp + take((size_t)Ee * EC * 4));
    int*   csrNe = (int*)  (wsp + take((size_t)Nn * NC * 4));
    int*   csrNs = (int*)  (wsp + take((size_t)Nn * NC * 4));
    unsigned* e4b = (unsigned*)(wsp + take((size_t)Ee * DOUT * 2));   // bf16
    unsigned* G1b = (unsigned*)(wsp + take((size_t)Ee * DOUT * 2));   // bf16
    unsigned* G2b = (unsigned*)(wsp + take((size_t)Ee * DOUT * 2));   // bf16
    short* W2T   = (short*)(wsp + take((size_t)DOUT * DIN * 2));   // bf16 [n][k]
    short* WWT   = (short*)(wsp + take((size_t)DOUT * DIN * 2));   // bf16 [c][r]
    float* bW3   = (float*)(wsp + take(DOUT * 4));
    (void)ws_size; (void)in_sizes; (void)n_in; (void)out_size;

    k_ww3   <<<105,     256, 0, stream>>>(W, W2, W3, bias, W2T, WWT, bW3,
                                          (uint4*)d_ws, (unsigned)(zbytes / 16));
    k_gemm1f<<<Nn / 16, 256, 0, stream>>>(x, W2T, WWT, bW3, q, hidx,
                                          bitmap, degE, degN, csrEn, csrNe, csrNs,
                                          x4b, xwb, rowv, csx4, csxw);
    k_edge1 <<<Ee / 4,  256, 0, stream>>>(degE, csrEn, rowv, csx4, csxw,
                                          (const unsigned*)x4b, (const unsigned*)xwb,
                                          Sval, e4b, G1b, wsArr, c2g);
    k_node2 <<<Nn / 8,  256, 0, stream>>>(degN, csrNe, csrNs,
                                          (const unsigned*)x4b, e4b, wsArr,
                                          Tval, vArr, vxg, twxg, wsxg);
    k_g2    <<<Ee / 4,  256, 0, stream>>>(degE, csrEn, Tval, vxg,
                                          (const unsigned*)x4b, G2b);
    k_final <<<Nn / 4,  256, 0, stream>>>(degN, csrNe, csrNs, Sval, Tval, vArr,
                                          c2g, csx4, wsxg, vxg, twxg, G1b, G2b, out);
}